// Round 10
// baseline (1367.595 us; speedup 1.0000x reference)
//
#include <hip/hip_runtime.h>
#include <math.h>
#include <stdint.h>

// Problem constants
#define NQ 8
#define DIMV 256
#define KCODES 1024
#define NTOK 65536              // 32*2048
#define NELEM (NTOK * DIMV)     // 16777216
#define TOKPB 64                // tokens per block in fused kernel

typedef _Float16 f16x8 __attribute__((ext_vector_type(8)));
typedef float    f32x16 __attribute__((ext_vector_type(16)));

// rotate-left-3 of a 5-bit slot index (bijective bank-spreading permutation)
__device__ __forceinline__ int rotl3(int s) { return ((s << 3) | (s >> 2)) & 31; }

// ---------------------------------------------------------------------------
// Pre-pass 1: transpose embeds [q][d][k] -> embedT [q][k][d] (fp32, for the
// quantize gather in the update phase).
// ---------------------------------------------------------------------------
__global__ __launch_bounds__(256)
void vq_transpose(const float* __restrict__ embeds, float* __restrict__ embedT) {
    const int idx = blockIdx.x * 256 + threadIdx.x;       // 0 .. 2097151
    const int q   = idx >> 18;
    const int rem = idx & 262143;
    const int k   = rem >> 8;
    const int d   = rem & 255;
    embedT[idx] = embeds[q * 262144 + d * 1024 + k];
}

// Pre-pass 2: e2[q][k] = sum_d embed[q][d][k]^2 (fp32)
__global__ __launch_bounds__(256)
void vq_e2(const float* __restrict__ embeds, float* __restrict__ e2) {
    const int idx = blockIdx.x * 256 + threadIdx.x;       // 0 .. 8191
    const int q = idx >> 10;
    const int k = idx & 1023;
    const float* e = embeds + q * 262144 + k;
    float s = 0.f;
    for (int d = 0; d < DIMV; ++d) {
        const float v = e[d * 1024];
        s += v * v;
    }
    e2[idx] = s;
}

// ---------------------------------------------------------------------------
// Pre-pass 3: split embed into fp16 hi/lo laid out as per-(layer,chunk,range)
// 4 KB images read straight into registers by the fused kernel:
//   embedB[q][chunk(16)][w(16)][part(2)][s(128)][j(8)]   (halfs)
// s = h*64 + cl ; d = chunk*16 + h*8 + j ; k = w*64 + cl
// Fragment read: lane(l32,h32), sub-tile ct -> s = h32*64 + ct*32 + l32
// (lane-contiguous 16B slots -> one coalesced global_load_dwordx4).
// ---------------------------------------------------------------------------
__global__ __launch_bounds__(256)
void vq_embedB(const float* __restrict__ embeds, _Float16* __restrict__ embedB) {
    const int idx = blockIdx.x * 256 + threadIdx.x;       // 0 .. 4194303
    const int j    = idx & 7;
    const int s    = (idx >> 3) & 127;
    const int part = (idx >> 10) & 1;
    const int w    = (idx >> 11) & 15;
    const int c    = (idx >> 15) & 15;
    const int q    = idx >> 19;
    const int h  = s >> 6;
    const int cl = s & 63;
    const int d  = c * 16 + h * 8 + j;
    const int k  = w * 64 + cl;
    const float v = embeds[q * 262144 + d * 1024 + k];
    const _Float16 hi = (_Float16)v;
    embedB[idx] = (part == 0) ? hi : (_Float16)(v - (float)hi);
}

// ---------------------------------------------------------------------------
// Fused 8-layer VQ kernel (round-10): 1024 blocks x 512 threads (8 waves),
// 64 tokens/block, residual LDS-resident across layers (r9 structure) plus:
//  - depth-3 B prefetch (4-slot rotation): covers ~580cy of matrix work vs
//    HBM-miss ~900cy (r9 depth-2 covered only ~380cy; FETCH showed 600+MB
//    of embedB/embedT HBM misses stalling waves).
//  - 2 barriers/layer (was 3+2 reduce phases): the cross-wave argmin's
//    (t,g)=(tid>>3,tid&7) mapping equals the update phase's (tl,sg), so
//    after the 8-way shuffle merge every thread holds its token's winning
//    code -> argmin+gather+update fuse, indF/lossRed LDS phases deleted.
//    Race-free: layer-top barrier separates layer-q bestS reads from
//    layer-q+1 bestS writes; update rows are wave-disjoint.
//  - XCD-chunked bijective block swizzle for x/out L2 locality.
// ---------------------------------------------------------------------------
// LDS layout (bytes):
//  [0,     32768)  A_hi : 64 rows x 256 d fp16; 16B-block s of row t at
//                         slot rotl3(s)^(t&31)
//  [32768, 65536)  A_lo : same layout
//  [65536, 67616)  bestS  float[8][65]  (stride 65: bank-spread)
//  [67616, 69696)  bestI  int  [8][65]
//  [69696, 73792)  e2Lds  float[1024]
#define LDS_BYTES 73792

__global__ __launch_bounds__(512, 4)
void vq_fused(const float* __restrict__ x, float* __restrict__ out,
              const float* __restrict__ embedT, const float* __restrict__ e2,
              const _Float16* __restrict__ embedB,
              float* __restrict__ lossSum, int* __restrict__ counts) {
    extern __shared__ char smem[];
    _Float16* Ahi = (_Float16*)smem;
    _Float16* Alo = (_Float16*)(smem + 32768);
    float* bestS   = (float*)(smem + 65536);
    int*   bestI   = (int*)(smem + 67616);
    float* e2Lds   = (float*)(smem + 69696);

    const int tid    = threadIdx.x;
    const int wave   = tid >> 6;       // 0..7
    const int lane   = tid & 63;
    const int l32    = lane & 31;
    const int h32    = lane >> 5;
    // XCD-chunked bijection (1024 blocks, 8 XCDs): physical dispatch
    // round-robins bid%8 across XCDs -> XCD k works contiguous tile range.
    const int bid0 = blockIdx.x;
    const int bid  = ((bid0 & 7) << 7) | (bid0 >> 3);
    const int tok0 = bid * TOKPB;

    // ---- stage x -> A hi/lo (swizzled), ONCE for all 8 layers ----
#pragma unroll
    for (int k = 0; k < 4; ++k) {
        const int si = tid + k * 512;          // 0..2047 (t,s) pairs
        const int t  = si >> 5;
        const int s  = si & 31;
        const float4 v0 = *(const float4*)(x + (tok0 + t) * 256 + s * 8);
        const float4 v1 = *(const float4*)(x + (tok0 + t) * 256 + s * 8 + 4);
        const float vv[8] = {v0.x, v0.y, v0.z, v0.w, v1.x, v1.y, v1.z, v1.w};
        f16x8 h8, l8;
#pragma unroll
        for (int e = 0; e < 8; ++e) {
            const _Float16 hi = (_Float16)vv[e];
            h8[e] = hi;
            l8[e] = (_Float16)(vv[e] - (float)hi);
        }
        const int ss = rotl3(s) ^ (t & 31);
        ((f16x8*)(Ahi + t * 256))[ss] = h8;
        ((f16x8*)(Alo + t * 256))[ss] = l8;
    }

    // ---- 8 residual-VQ layers, residual resident in LDS ----
#pragma unroll 1
    for (int q = 0; q < NQ; ++q) {
        const _Float16* embedBq = embedB + q * 524288;
        const float*    embedTq = embedT + q * (KCODES * DIMV);

        // stage this layer's e2 into LDS (broadcast-read in score phase)
        e2Lds[tid]       = e2[q * KCODES + tid];
        e2Lds[tid + 512] = e2[q * KCODES + tid + 512];
        // BARRIER 1: covers initial/updated A writes + e2 writes; also
        // separates prev layer's bestS reads from this layer's writes.
        __syncthreads();

        // running per-token best over this wave's 128 codes
        float bsv0 = 3.4e38f, bsv1 = 3.4e38f;
        int   biv0 = 0x7fffffff, biv1 = 0x7fffffff;

        // ---- four 32-code passes: acc[2] = 32 AGPR, depth-3 B prefetch ----
#pragma unroll
        for (int p = 0; p < 4; ++p) {
            f32x16 acc[2];
#pragma unroll
            for (int tt = 0; tt < 2; ++tt)
#pragma unroll
                for (int r = 0; r < 16; ++r) acc[tt][r] = 0.f;

            // image (2*wave + p>>1) covers codes [wave*128+(p>>1)*64, +64);
            // (p&1) selects the 32-code half (ct offset 512 B).
            const char* gBp = (const char*)embedBq + (2 * wave + (p >> 1)) * 4096
                              + (p & 1) * 512 + h32 * 1024 + l32 * 16;

            // 4-slot rotating prefetch buffer, depth 3 (indices compile-time)
            f16x8 bH[4], bL[4];
            bH[0] = *(const f16x8*)(gBp);
            bL[0] = *(const f16x8*)(gBp + 2048);
            bH[1] = *(const f16x8*)(gBp + 65536);
            bL[1] = *(const f16x8*)(gBp + 65536 + 2048);
            bH[2] = *(const f16x8*)(gBp + 131072);
            bL[2] = *(const f16x8*)(gBp + 131072 + 2048);

#pragma unroll
            for (int c = 0; c < 16; ++c) {
                const int cs = c & 3;
                if (c < 13) {
                    const char* gBn = gBp + (c + 3) * 65536;
                    bH[(c + 3) & 3] = *(const f16x8*)(gBn);
                    bL[(c + 3) & 3] = *(const f16x8*)(gBn + 2048);
                }
                f16x8 aH[2], aL[2];
#pragma unroll
                for (int tt = 0; tt < 2; ++tt) {
                    const int t  = tt * 32 + l32;
                    const int ss = rotl3(2 * c + h32) ^ l32;
                    aH[tt] = ((const f16x8*)(Ahi + t * 256))[ss];
                    aL[tt] = ((const f16x8*)(Alo + t * 256))[ss];
                }
                // swapped operands: D[code_row][token_col]; per-tile chain
                // order (H*H, L*H, H*L; chunks ascending) identical to the
                // verified kernel -> bit-identical scores.
#pragma unroll
                for (int tt = 0; tt < 2; ++tt) {
                    acc[tt] = __builtin_amdgcn_mfma_f32_32x32x16_f16(
                        bH[cs], aH[tt], acc[tt], 0, 0, 0);
                    acc[tt] = __builtin_amdgcn_mfma_f32_32x32x16_f16(
                        bL[cs], aH[tt], acc[tt], 0, 0, 0);
                    acc[tt] = __builtin_amdgcn_mfma_f32_32x32x16_f16(
                        bH[cs], aL[tt], acc[tt], 0, 0, 0);
                }
            }

            // scores for this pass's 32 codes; fold into running best
#pragma unroll
            for (int tt = 0; tt < 2; ++tt) {
                float bs = (tt == 0) ? bsv0 : bsv1;
                int   bi = (tt == 0) ? biv0 : biv1;
#pragma unroll
                for (int r = 0; r < 16; ++r) {
                    const int cd = wave * 128 + p * 32 + (r & 3) + 8 * (r >> 2) + 4 * h32;
                    const float sc = e2Lds[cd] - 2.0f * acc[tt][r];
                    if (sc < bs || (sc == bs && cd < bi)) { bs = sc; bi = cd; }
                }
                if (tt == 0) { bsv0 = bs; biv0 = bi; } else { bsv1 = bs; biv1 = bi; }
            }
        }

        // ---- merge with the other 32-lane half, write per-wave best ----
#pragma unroll
        for (int tt = 0; tt < 2; ++tt) {
            float bs = (tt == 0) ? bsv0 : bsv1;
            int   bi = (tt == 0) ? biv0 : biv1;
            const float so = __shfl_xor(bs, 32);
            const int   io = __shfl_xor(bi, 32);
            if (so < bs || (so == bs && io < bi)) { bs = so; bi = io; }
            if (h32 == 0) {
                bestS[wave * 65 + tt * 32 + l32] = bs;
                bestI[wave * 65 + tt * 32 + l32] = bi;
            }
        }
        // BARRIER 2: bestS/bestI visible; separates K-loop A-reads from
        // the update phase's A-writes.
        __syncthreads();

        // ---- fused argmin + update (no barrier between):
        // thread (t=tid>>3, g=tid&7) merges 8 wave-entries for token t via
        // shuffle; afterwards EVERY thread holds the winning code for its
        // token, which is exactly the update phase's (tl,sg) mapping.
        {
            const int tl = tid >> 3;          // token 0..63
            const int g  = tid & 7;           // wave index / 32-dim strip
            float bs = bestS[g * 65 + tl];
            int   bi = bestI[g * 65 + tl];
#pragma unroll
            for (int m = 1; m < 8; m <<= 1) {
                const float so = __shfl_xor(bs, m);
                const int   io = __shfl_xor(bi, m);
                if (so < bs || (so == bs && io < bi)) { bs = so; bi = io; }
            }
            if (g == 0) atomicAdd(&counts[q * KCODES + bi], 1);

            // update: r -= quantize (in LDS); loss partial
            const float* gq = embedTq + bi * 256;
            float lp = 0.f;
            f16x8* rowH = (f16x8*)(Ahi + tl * 256);
            f16x8* rowL = (f16x8*)(Alo + tl * 256);
#pragma unroll
            for (int it = 0; it < 4; ++it) {
                const int slotIdx = g * 4 + it;           // 0..31
                const int slot = rotl3(slotIdx) ^ (tl & 31);
                f16x8 h8 = rowH[slot];
                f16x8 l8 = rowL[slot];
                const float4 q0 = *(const float4*)(gq + slotIdx * 8);
                const float4 q1 = *(const float4*)(gq + slotIdx * 8 + 4);
                const float qv[8] = {q0.x, q0.y, q0.z, q0.w, q1.x, q1.y, q1.z, q1.w};
#pragma unroll
                for (int e = 0; e < 8; ++e) {
                    const float rv = (float)h8[e] + (float)l8[e];
                    const float nr = rv - qv[e];
                    lp += nr * nr;
                    const _Float16 nh = (_Float16)nr;
                    h8[e] = nh;
                    l8[e] = (_Float16)(nr - (float)nh);
                }
                rowH[slot] = h8;
                rowL[slot] = l8;
            }
            // loss: wave-level shuffle reduce -> one global atomic per wave
#pragma unroll
            for (int off = 32; off > 0; off >>= 1) lp += __shfl_down(lp, off);
            if (lane == 0) atomicAdd(lossSum + q, lp);
        }
        // no trailing barrier: next layer's top barrier fences A/bestS.
    }

    __syncthreads();   // final update writes -> writeback reads

    // ---- writeback: out = x - residual_final, coalesced ----
#pragma unroll
    for (int k = 0; k < 4; ++k) {
        const int si = tid + k * 512;
        const int t  = si >> 5;
        const int s  = si & 31;
        const int ss = rotl3(s) ^ (t & 31);
        const f16x8 h8 = ((const f16x8*)(Ahi + t * 256))[ss];
        const f16x8 l8 = ((const f16x8*)(Alo + t * 256))[ss];
        const float4 x0 = *(const float4*)(x + (tok0 + t) * 256 + s * 8);
        const float4 x1 = *(const float4*)(x + (tok0 + t) * 256 + s * 8 + 4);
        float4 o0, o1;
        o0.x = x0.x - ((float)h8[0] + (float)l8[0]);
        o0.y = x0.y - ((float)h8[1] + (float)l8[1]);
        o0.z = x0.z - ((float)h8[2] + (float)l8[2]);
        o0.w = x0.w - ((float)h8[3] + (float)l8[3]);
        o1.x = x1.x - ((float)h8[4] + (float)l8[4]);
        o1.y = x1.y - ((float)h8[5] + (float)l8[5]);
        o1.z = x1.z - ((float)h8[6] + (float)l8[6]);
        o1.w = x1.w - ((float)h8[7] + (float)l8[7]);
        *(float4*)(out + (tok0 + t) * 256 + s * 8)     = o0;
        *(float4*)(out + (tok0 + t) * 256 + s * 8 + 4) = o1;
    }
}

// ---------------------------------------------------------------------------
// Finalize: losses + perplexities into the output tail.
// ---------------------------------------------------------------------------
__global__ __launch_bounds__(256)
void vq_finalize(const int* __restrict__ counts, const float* __restrict__ lossSum,
                 float* __restrict__ outTail) {
    const int q = blockIdx.x;
    const int tid = threadIdx.x;
    float s = 0.f;
    for (int k = tid; k < KCODES; k += 256) {
        const float p = (float)counts[q * KCODES + k] * (1.0f / 65536.0f);
        s += p * logf(p + 1e-10f);
    }
    for (int off = 32; off > 0; off >>= 1) s += __shfl_down(s, off);
    __shared__ float wpart[4];
    if ((tid & 63) == 0) wpart[tid >> 6] = s;
    __syncthreads();
    if (tid == 0) {
        outTail[q]     = lossSum[q] * (1.0f / 16777216.0f);   // mean * COMMITMENT
        outTail[8 + q] = expf(-(wpart[0] + wpart[1] + wpart[2] + wpart[3]));
    }
}

// ---------------------------------------------------------------------------
extern "C" void kernel_launch(void* const* d_in, const int* in_sizes, int n_in,
                              void* d_out, int out_size, void* d_ws, size_t ws_size,
                              hipStream_t stream) {
    const float* x      = (const float*)d_in[0];   // [32,2048,256]
    const float* embeds = (const float*)d_in[1];   // [8,256,1024]
    float* out = (float*)d_out;                    // 16777216 + 8 + 8

    // Workspace layout (float units unless noted):
    float* embedT   = (float*)d_ws;                     // 2,097,152
    float* e2       = embedT + 2097152;                 // 8,192
    float* lossSum  = e2 + 8192;                        // 8
    int*   counts   = (int*)(lossSum + 8);              // 8,192
    _Float16* embedB = (_Float16*)(counts + 8192);      // 4,194,304 halfs (8 MB)

    hipMemsetAsync(lossSum, 0, (8 + 8192) * sizeof(float), stream);

    vq_transpose<<<8192, 256, 0, stream>>>(embeds, embedT);
    vq_e2<<<32, 256, 0, stream>>>(embeds, e2);
    vq_embedB<<<16384, 256, 0, stream>>>(embeds, embedB);

    hipFuncSetAttribute((const void*)vq_fused,
                        hipFuncAttributeMaxDynamicSharedMemorySize, LDS_BYTES);
    vq_fused<<<NTOK / TOKPB, 512, LDS_BYTES, stream>>>(
        x, out, embedT, e2, embedB, lossSum, counts);

    vq_finalize<<<NQ, 256, 0, stream>>>(counts, lossSum, out + NELEM);
}

// Round 11
// 1277.339 us; speedup vs baseline: 1.0707x; 1.0707x over previous
//
#include <hip/hip_runtime.h>
#include <math.h>
#include <stdint.h>

// Problem constants
#define NQ 8
#define DIMV 256
#define KCODES 1024
#define NTOK 65536              // 32*2048
#define NELEM (NTOK * DIMV)     // 16777216
#define TOKPB 64                // tokens per block in fused kernel

typedef _Float16 f16x8 __attribute__((ext_vector_type(8)));
typedef float    f32x16 __attribute__((ext_vector_type(16)));

// rotate-left-3 of a 5-bit slot index (bijective bank-spreading permutation)
__device__ __forceinline__ int rotl3(int s) { return ((s << 3) | (s >> 2)) & 31; }

// ---------------------------------------------------------------------------
// Pre-pass 1: transpose embeds [q][d][k] -> embedT [q][k][d] (fp32, for the
// quantize gather in the update phase).
// ---------------------------------------------------------------------------
__global__ __launch_bounds__(256)
void vq_transpose(const float* __restrict__ embeds, float* __restrict__ embedT) {
    const int idx = blockIdx.x * 256 + threadIdx.x;       // 0 .. 2097151
    const int q   = idx >> 18;
    const int rem = idx & 262143;
    const int k   = rem >> 8;
    const int d   = rem & 255;
    embedT[idx] = embeds[q * 262144 + d * 1024 + k];
}

// Pre-pass 2: e2[q][k] = sum_d embed[q][d][k]^2 (fp32)
__global__ __launch_bounds__(256)
void vq_e2(const float* __restrict__ embeds, float* __restrict__ e2) {
    const int idx = blockIdx.x * 256 + threadIdx.x;       // 0 .. 8191
    const int q = idx >> 10;
    const int k = idx & 1023;
    const float* e = embeds + q * 262144 + k;
    float s = 0.f;
    for (int d = 0; d < DIMV; ++d) {
        const float v = e[d * 1024];
        s += v * v;
    }
    e2[idx] = s;
}

// ---------------------------------------------------------------------------
// Pre-pass 3: split embed into fp16 hi/lo laid out as per-(layer,chunk,range)
// 4 KB images read straight into registers by the fused kernel:
//   embedB[q][chunk(16)][w(16)][part(2)][s(128)][j(8)]   (halfs)
// s = h*64 + cl ; d = chunk*16 + h*8 + j ; k = w*64 + cl
// Fragment read: lane(l32,h32), sub-tile ct -> s = h32*64 + ct*32 + l32
// (lane-contiguous 16B slots -> one coalesced global_load_dwordx4).
// ---------------------------------------------------------------------------
__global__ __launch_bounds__(256)
void vq_embedB(const float* __restrict__ embeds, _Float16* __restrict__ embedB) {
    const int idx = blockIdx.x * 256 + threadIdx.x;       // 0 .. 4194303
    const int j    = idx & 7;
    const int s    = (idx >> 3) & 127;
    const int part = (idx >> 10) & 1;
    const int w    = (idx >> 11) & 15;
    const int c    = (idx >> 15) & 15;
    const int q    = idx >> 19;
    const int h  = s >> 6;
    const int cl = s & 63;
    const int d  = c * 16 + h * 8 + j;
    const int k  = w * 64 + cl;
    const float v = embeds[q * 262144 + d * 1024 + k];
    const _Float16 hi = (_Float16)v;
    embedB[idx] = (part == 0) ? hi : (_Float16)(v - (float)hi);
}

// ---------------------------------------------------------------------------
// Fused 8-layer VQ kernel (round-11): r9 structure (measured best, 1190 us)
// -- 1024 blocks x 512 threads (8 waves), 64 tokens/block, residual in LDS,
// depth-2 B prefetch (3-slot), NO swizzle -- plus ONLY the clean barrier
// fusion from r10:
//  - 2 barriers/layer (was 3): cross-wave argmin's (tl,g)=(tid>>3,tid&7)
//    mapping equals the update phase's, so after the 8-way shuffle merge
//    every thread holds its token's winning code -> argmin+gather+update
//    fuse; the indF phase and its barrier are deleted.
//  - loss keeps ONE block atomic per layer (r10's 8 same-address atomics
//    per block regressed): per-wave partials -> lossRed[8] in LDS; the
//    8-float sum + atomic for layer q-1 is deferred into layer q's
//    post-barrier-1 region (lossRed(q-1) written pre-B1(q); lossRed(q)
//    not written until post-B2(q) -> race-free); layer 7 flushes after
//    the final barrier.
// ---------------------------------------------------------------------------
// LDS layout (bytes):
//  [0,     32768)  A_hi : 64 rows x 256 d fp16; 16B-block s of row t at
//                         slot rotl3(s)^(t&31)
//  [32768, 65536)  A_lo : same layout
//  [65536, 67616)  bestS  float[8][65]  (stride 65: bank-spread)
//  [67616, 69696)  bestI  int  [8][65]
//  [69696, 69728)  lossRed float[8]
//  [69728, 73824)  e2Lds  float[1024]
#define LDS_BYTES 73824

__global__ __launch_bounds__(512, 4)
void vq_fused(const float* __restrict__ x, float* __restrict__ out,
              const float* __restrict__ embedT, const float* __restrict__ e2,
              const _Float16* __restrict__ embedB,
              float* __restrict__ lossSum, int* __restrict__ counts) {
    extern __shared__ char smem[];
    _Float16* Ahi = (_Float16*)smem;
    _Float16* Alo = (_Float16*)(smem + 32768);
    float* bestS   = (float*)(smem + 65536);
    int*   bestI   = (int*)(smem + 67616);
    float* lossRed = (float*)(smem + 69696);
    float* e2Lds   = (float*)(smem + 69728);

    const int tid    = threadIdx.x;
    const int wave   = tid >> 6;       // 0..7
    const int lane   = tid & 63;
    const int l32    = lane & 31;
    const int h32    = lane >> 5;
    const int tok0   = blockIdx.x * TOKPB;

    // ---- stage x -> A hi/lo (swizzled), ONCE for all 8 layers ----
#pragma unroll
    for (int k = 0; k < 4; ++k) {
        const int si = tid + k * 512;          // 0..2047 (t,s) pairs
        const int t  = si >> 5;
        const int s  = si & 31;
        const float4 v0 = *(const float4*)(x + (tok0 + t) * 256 + s * 8);
        const float4 v1 = *(const float4*)(x + (tok0 + t) * 256 + s * 8 + 4);
        const float vv[8] = {v0.x, v0.y, v0.z, v0.w, v1.x, v1.y, v1.z, v1.w};
        f16x8 h8, l8;
#pragma unroll
        for (int e = 0; e < 8; ++e) {
            const _Float16 hi = (_Float16)vv[e];
            h8[e] = hi;
            l8[e] = (_Float16)(vv[e] - (float)hi);
        }
        const int ss = rotl3(s) ^ (t & 31);
        ((f16x8*)(Ahi + t * 256))[ss] = h8;
        ((f16x8*)(Alo + t * 256))[ss] = l8;
    }

    // ---- 8 residual-VQ layers, residual resident in LDS ----
#pragma unroll 1
    for (int q = 0; q < NQ; ++q) {
        const _Float16* embedBq = embedB + q * 524288;
        const float*    embedTq = embedT + q * (KCODES * DIMV);

        // stage this layer's e2 into LDS (broadcast-read in score phase)
        e2Lds[tid]       = e2[q * KCODES + tid];
        e2Lds[tid + 512] = e2[q * KCODES + tid + 512];
        // BARRIER 1: fences A/e2 writes; also orders prev layer's bestS
        // reads (fused phase) before this layer's bestS writes, and prev
        // layer's lossRed writes before the deferred read below.
        __syncthreads();

        // deferred loss flush for layer q-1: one atomic per block per layer
        if (q > 0 && tid == 0) {
            float t = 0.f;
#pragma unroll
            for (int w = 0; w < 8; ++w) t += lossRed[w];
            atomicAdd(lossSum + (q - 1), t);
        }

        // running per-token best over this wave's 128 codes
        float bsv0 = 3.4e38f, bsv1 = 3.4e38f;
        int   biv0 = 0x7fffffff, biv1 = 0x7fffffff;

        // ---- four 32-code passes: acc[2] = 32 AGPR, depth-2 B prefetch ----
#pragma unroll
        for (int p = 0; p < 4; ++p) {
            f32x16 acc[2];
#pragma unroll
            for (int tt = 0; tt < 2; ++tt)
#pragma unroll
                for (int r = 0; r < 16; ++r) acc[tt][r] = 0.f;

            // image (2*wave + p>>1) covers codes [wave*128+(p>>1)*64, +64);
            // (p&1) selects the 32-code half (ct offset 512 B).
            const char* gBp = (const char*)embedBq + (2 * wave + (p >> 1)) * 4096
                              + (p & 1) * 512 + h32 * 1024 + l32 * 16;

            // 3-slot rotating prefetch buffer (all indices compile-time)
            f16x8 bH[3], bL[3];
            bH[0] = *(const f16x8*)(gBp);
            bL[0] = *(const f16x8*)(gBp + 2048);
            bH[1] = *(const f16x8*)(gBp + 65536);
            bL[1] = *(const f16x8*)(gBp + 65536 + 2048);

#pragma unroll
            for (int c = 0; c < 16; ++c) {
                const int cs = c % 3;
                if (c < 14) {
                    const char* gBn = gBp + (c + 2) * 65536;
                    bH[(c + 2) % 3] = *(const f16x8*)(gBn);
                    bL[(c + 2) % 3] = *(const f16x8*)(gBn + 2048);
                }
                f16x8 aH[2], aL[2];
#pragma unroll
                for (int tt = 0; tt < 2; ++tt) {
                    const int t  = tt * 32 + l32;
                    const int ss = rotl3(2 * c + h32) ^ l32;
                    aH[tt] = ((const f16x8*)(Ahi + t * 256))[ss];
                    aL[tt] = ((const f16x8*)(Alo + t * 256))[ss];
                }
                // swapped operands: D[code_row][token_col]; per-tile chain
                // order (H*H, L*H, H*L; chunks ascending) identical to the
                // verified kernel -> bit-identical scores.
#pragma unroll
                for (int tt = 0; tt < 2; ++tt) {
                    acc[tt] = __builtin_amdgcn_mfma_f32_32x32x16_f16(
                        bH[cs], aH[tt], acc[tt], 0, 0, 0);
                    acc[tt] = __builtin_amdgcn_mfma_f32_32x32x16_f16(
                        bL[cs], aH[tt], acc[tt], 0, 0, 0);
                    acc[tt] = __builtin_amdgcn_mfma_f32_32x32x16_f16(
                        bH[cs], aL[tt], acc[tt], 0, 0, 0);
                }
            }

            // scores for this pass's 32 codes; fold into running best
#pragma unroll
            for (int tt = 0; tt < 2; ++tt) {
                float bs = (tt == 0) ? bsv0 : bsv1;
                int   bi = (tt == 0) ? biv0 : biv1;
#pragma unroll
                for (int r = 0; r < 16; ++r) {
                    const int cd = wave * 128 + p * 32 + (r & 3) + 8 * (r >> 2) + 4 * h32;
                    const float sc = e2Lds[cd] - 2.0f * acc[tt][r];
                    if (sc < bs || (sc == bs && cd < bi)) { bs = sc; bi = cd; }
                }
                if (tt == 0) { bsv0 = bs; biv0 = bi; } else { bsv1 = bs; biv1 = bi; }
            }
        }

        // ---- merge with the other 32-lane half, write per-wave best ----
#pragma unroll
        for (int tt = 0; tt < 2; ++tt) {
            float bs = (tt == 0) ? bsv0 : bsv1;
            int   bi = (tt == 0) ? biv0 : biv1;
            const float so = __shfl_xor(bs, 32);
            const int   io = __shfl_xor(bi, 32);
            if (so < bs || (so == bs && io < bi)) { bs = so; bi = io; }
            if (h32 == 0) {
                bestS[wave * 65 + tt * 32 + l32] = bs;
                bestI[wave * 65 + tt * 32 + l32] = bi;
            }
        }
        // BARRIER 2: bestS/bestI visible; separates K-loop A-reads from
        // the update phase's A-writes.
        __syncthreads();

        // ---- fused argmin + gather + update (no extra barrier):
        // thread (tl=tid>>3, g=tid&7) merges the 8 wave-entries for its
        // token via shuffle; afterwards EVERY thread holds the winning
        // code, which is exactly the update phase's (tl,sg) mapping.
        {
            const int tl = tid >> 3;          // token 0..63
            const int g  = tid & 7;           // wave index / 32-dim strip
            float bs = bestS[g * 65 + tl];
            int   bi = bestI[g * 65 + tl];
#pragma unroll
            for (int m = 1; m < 8; m <<= 1) {
                const float so = __shfl_xor(bs, m);
                const int   io = __shfl_xor(bi, m);
                if (so < bs || (so == bs && io < bi)) { bs = so; bi = io; }
            }
            if (g == 0) atomicAdd(&counts[q * KCODES + bi], 1);

            // update: r -= quantize (in LDS); loss partial
            const float* gq = embedTq + bi * 256;
            float lp = 0.f;
            f16x8* rowH = (f16x8*)(Ahi + tl * 256);
            f16x8* rowL = (f16x8*)(Alo + tl * 256);
#pragma unroll
            for (int it = 0; it < 4; ++it) {
                const int slotIdx = g * 4 + it;           // 0..31
                const int slot = rotl3(slotIdx) ^ (tl & 31);
                f16x8 h8 = rowH[slot];
                f16x8 l8 = rowL[slot];
                const float4 q0 = *(const float4*)(gq + slotIdx * 8);
                const float4 q1 = *(const float4*)(gq + slotIdx * 8 + 4);
                const float qv[8] = {q0.x, q0.y, q0.z, q0.w, q1.x, q1.y, q1.z, q1.w};
#pragma unroll
                for (int e = 0; e < 8; ++e) {
                    const float rv = (float)h8[e] + (float)l8[e];
                    const float nr = rv - qv[e];
                    lp += nr * nr;
                    const _Float16 nh = (_Float16)nr;
                    h8[e] = nh;
                    l8[e] = (_Float16)(nr - (float)nh);
                }
                rowH[slot] = h8;
                rowL[slot] = l8;
            }
            // loss: wave shuffle-reduce -> lossRed[wave] (flushed next layer)
#pragma unroll
            for (int off = 32; off > 0; off >>= 1) lp += __shfl_down(lp, off);
            if (lane == 0) lossRed[wave] = lp;
        }
        // no trailing barrier: next layer's B1 fences A/bestS/lossRed.
    }

    __syncthreads();   // final update + lossRed writes -> reads below

    // deferred loss flush for the last layer
    if (tid == 0) {
        float t = 0.f;
#pragma unroll
        for (int w = 0; w < 8; ++w) t += lossRed[w];
        atomicAdd(lossSum + (NQ - 1), t);
    }

    // ---- writeback: out = x - residual_final, coalesced ----
#pragma unroll
    for (int k = 0; k < 4; ++k) {
        const int si = tid + k * 512;
        const int t  = si >> 5;
        const int s  = si & 31;
        const int ss = rotl3(s) ^ (t & 31);
        const f16x8 h8 = ((const f16x8*)(Ahi + t * 256))[ss];
        const f16x8 l8 = ((const f16x8*)(Alo + t * 256))[ss];
        const float4 x0 = *(const float4*)(x + (tok0 + t) * 256 + s * 8);
        const float4 x1 = *(const float4*)(x + (tok0 + t) * 256 + s * 8 + 4);
        float4 o0, o1;
        o0.x = x0.x - ((float)h8[0] + (float)l8[0]);
        o0.y = x0.y - ((float)h8[1] + (float)l8[1]);
        o0.z = x0.z - ((float)h8[2] + (float)l8[2]);
        o0.w = x0.w - ((float)h8[3] + (float)l8[3]);
        o1.x = x1.x - ((float)h8[4] + (float)l8[4]);
        o1.y = x1.y - ((float)h8[5] + (float)l8[5]);
        o1.z = x1.z - ((float)h8[6] + (float)l8[6]);
        o1.w = x1.w - ((float)h8[7] + (float)l8[7]);
        *(float4*)(out + (tok0 + t) * 256 + s * 8)     = o0;
        *(float4*)(out + (tok0 + t) * 256 + s * 8 + 4) = o1;
    }
}

// ---------------------------------------------------------------------------
// Finalize: losses + perplexities into the output tail.
// ---------------------------------------------------------------------------
__global__ __launch_bounds__(256)
void vq_finalize(const int* __restrict__ counts, const float* __restrict__ lossSum,
                 float* __restrict__ outTail) {
    const int q = blockIdx.x;
    const int tid = threadIdx.x;
    float s = 0.f;
    for (int k = tid; k < KCODES; k += 256) {
        const float p = (float)counts[q * KCODES + k] * (1.0f / 65536.0f);
        s += p * logf(p + 1e-10f);
    }
    for (int off = 32; off > 0; off >>= 1) s += __shfl_down(s, off);
    __shared__ float wpart[4];
    if ((tid & 63) == 0) wpart[tid >> 6] = s;
    __syncthreads();
    if (tid == 0) {
        outTail[q]     = lossSum[q] * (1.0f / 16777216.0f);   // mean * COMMITMENT
        outTail[8 + q] = expf(-(wpart[0] + wpart[1] + wpart[2] + wpart[3]));
    }
}

// ---------------------------------------------------------------------------
extern "C" void kernel_launch(void* const* d_in, const int* in_sizes, int n_in,
                              void* d_out, int out_size, void* d_ws, size_t ws_size,
                              hipStream_t stream) {
    const float* x      = (const float*)d_in[0];   // [32,2048,256]
    const float* embeds = (const float*)d_in[1];   // [8,256,1024]
    float* out = (float*)d_out;                    // 16777216 + 8 + 8

    // Workspace layout (float units unless noted):
    float* embedT   = (float*)d_ws;                     // 2,097,152
    float* e2       = embedT + 2097152;                 // 8,192
    float* lossSum  = e2 + 8192;                        // 8
    int*   counts   = (int*)(lossSum + 8);              // 8,192
    _Float16* embedB = (_Float16*)(counts + 8192);      // 4,194,304 halfs (8 MB)

    hipMemsetAsync(lossSum, 0, (8 + 8192) * sizeof(float), stream);

    vq_transpose<<<8192, 256, 0, stream>>>(embeds, embedT);
    vq_e2<<<32, 256, 0, stream>>>(embeds, e2);
    vq_embedB<<<16384, 256, 0, stream>>>(embeds, embedB);

    hipFuncSetAttribute((const void*)vq_fused,
                        hipFuncAttributeMaxDynamicSharedMemorySize, LDS_BYTES);
    vq_fused<<<NTOK / TOKPB, 512, LDS_BYTES, stream>>>(
        x, out, embedT, e2, embedB, lossSum, counts);

    vq_finalize<<<NQ, 256, 0, stream>>>(counts, lossSum, out + NELEM);
}

// Round 12
// 1175.102 us; speedup vs baseline: 1.1638x; 1.0870x over previous
//
#include <hip/hip_runtime.h>
#include <math.h>
#include <stdint.h>

// Problem constants
#define NQ 8
#define DIMV 256
#define KCODES 1024
#define NTOK 65536              // 32*2048
#define NELEM (NTOK * DIMV)     // 16777216
#define TOKPB 64                // tokens per block in fused kernel

typedef _Float16 f16x8 __attribute__((ext_vector_type(8)));
typedef float    f32x16 __attribute__((ext_vector_type(16)));

// rotate-left-3 of a 5-bit slot index (bijective bank-spreading permutation)
__device__ __forceinline__ int rotl3(int s) { return ((s << 3) | (s >> 2)) & 31; }

// ---------------------------------------------------------------------------
// Pre-pass 1: transpose embeds [q][d][k] -> embedT [q][k][d] (fp32, for the
// quantize gather in the update phase).
// ---------------------------------------------------------------------------
__global__ __launch_bounds__(256)
void vq_transpose(const float* __restrict__ embeds, float* __restrict__ embedT) {
    const int idx = blockIdx.x * 256 + threadIdx.x;       // 0 .. 2097151
    const int q   = idx >> 18;
    const int rem = idx & 262143;
    const int k   = rem >> 8;
    const int d   = rem & 255;
    embedT[idx] = embeds[q * 262144 + d * 1024 + k];
}

// Pre-pass 2: e2[q][k] = sum_d embed[q][d][k]^2 (fp32)
__global__ __launch_bounds__(256)
void vq_e2(const float* __restrict__ embeds, float* __restrict__ e2) {
    const int idx = blockIdx.x * 256 + threadIdx.x;       // 0 .. 8191
    const int q = idx >> 10;
    const int k = idx & 1023;
    const float* e = embeds + q * 262144 + k;
    float s = 0.f;
    for (int d = 0; d < DIMV; ++d) {
        const float v = e[d * 1024];
        s += v * v;
    }
    e2[idx] = s;
}

// ---------------------------------------------------------------------------
// Pre-pass 3: split embed into fp16 hi/lo laid out as per-(layer,chunk,range)
// 4 KB images read straight into registers by the fused kernel:
//   embedB[q][chunk(16)][w(16)][part(2)][s(128)][j(8)]   (halfs)
// s = h*64 + cl ; d = chunk*16 + h*8 + j ; k = w*64 + cl
// Fragment read: lane(l32,h32), sub-tile ct -> s = h32*64 + ct*32 + l32
// (lane-contiguous 16B slots -> one coalesced global_load_dwordx4).
// ---------------------------------------------------------------------------
__global__ __launch_bounds__(256)
void vq_embedB(const float* __restrict__ embeds, _Float16* __restrict__ embedB) {
    const int idx = blockIdx.x * 256 + threadIdx.x;       // 0 .. 4194303
    const int j    = idx & 7;
    const int s    = (idx >> 3) & 127;
    const int part = (idx >> 10) & 1;
    const int w    = (idx >> 11) & 15;
    const int c    = (idx >> 15) & 15;
    const int q    = idx >> 19;
    const int h  = s >> 6;
    const int cl = s & 63;
    const int d  = c * 16 + h * 8 + j;
    const int k  = w * 64 + cl;
    const float v = embeds[q * 262144 + d * 1024 + k];
    const _Float16 hi = (_Float16)v;
    embedB[idx] = (part == 0) ? hi : (_Float16)(v - (float)hi);
}

// ---------------------------------------------------------------------------
// Fused 8-layer VQ kernel (round-12): r11 structure (1024 blocks x 512
// threads, 64 tokens/block, residual in LDS, 2 barriers/layer, fused
// argmin+update, deferred loss) with a restructured K-loop:
//
// TWO CONCURRENT 32-code streams per pass-pair (acc[2][2] = 64 AGPR, both
// streams drawn from the SAME 4 KB B-image at ct offsets 0/512). The A
// fragments (aH/aL) are now shared by both streams, halving the A-tile
// LDS reads (256 -> 128 per wave per layer). Rationale: r11's counters
// show LDS-read pipe demand (~330 us) co-equal with MFMA (~330 us) while
// everything idles at <33% -- latency-bound with too little TLP (16
// waves/CU, LDS-capped); cutting LDS demand attacks the co-critical path.
// B is single-buffered per chunk (full unroll gives SSA-fresh B regs, so
// the scheduler can still hoist next-chunk loads into free regs). Per-code
// MFMA chain order (HH,LH,HL; chunks ascending) unchanged -> identical
// scores. Register budget: 64 acc + ~32 B + 16 A + misc <= 128 @ 4
// waves/SIMD (watch WRITE_SIZE for spill).
// ---------------------------------------------------------------------------
// LDS layout (bytes):
//  [0,     32768)  A_hi : 64 rows x 256 d fp16; 16B-block s of row t at
//                         slot rotl3(s)^(t&31)
//  [32768, 65536)  A_lo : same layout
//  [65536, 67616)  bestS  float[8][65]  (stride 65: bank-spread)
//  [67616, 69696)  bestI  int  [8][65]
//  [69696, 69728)  lossRed float[8]
//  [69728, 73824)  e2Lds  float[1024]
#define LDS_BYTES 73824

__global__ __launch_bounds__(512, 4)
void vq_fused(const float* __restrict__ x, float* __restrict__ out,
              const float* __restrict__ embedT, const float* __restrict__ e2,
              const _Float16* __restrict__ embedB,
              float* __restrict__ lossSum, int* __restrict__ counts) {
    extern __shared__ char smem[];
    _Float16* Ahi = (_Float16*)smem;
    _Float16* Alo = (_Float16*)(smem + 32768);
    float* bestS   = (float*)(smem + 65536);
    int*   bestI   = (int*)(smem + 67616);
    float* lossRed = (float*)(smem + 69696);
    float* e2Lds   = (float*)(smem + 69728);

    const int tid    = threadIdx.x;
    const int wave   = tid >> 6;       // 0..7
    const int lane   = tid & 63;
    const int l32    = lane & 31;
    const int h32    = lane >> 5;
    const int tok0   = blockIdx.x * TOKPB;

    // ---- stage x -> A hi/lo (swizzled), ONCE for all 8 layers ----
#pragma unroll
    for (int k = 0; k < 4; ++k) {
        const int si = tid + k * 512;          // 0..2047 (t,s) pairs
        const int t  = si >> 5;
        const int s  = si & 31;
        const float4 v0 = *(const float4*)(x + (tok0 + t) * 256 + s * 8);
        const float4 v1 = *(const float4*)(x + (tok0 + t) * 256 + s * 8 + 4);
        const float vv[8] = {v0.x, v0.y, v0.z, v0.w, v1.x, v1.y, v1.z, v1.w};
        f16x8 h8, l8;
#pragma unroll
        for (int e = 0; e < 8; ++e) {
            const _Float16 hi = (_Float16)vv[e];
            h8[e] = hi;
            l8[e] = (_Float16)(vv[e] - (float)hi);
        }
        const int ss = rotl3(s) ^ (t & 31);
        ((f16x8*)(Ahi + t * 256))[ss] = h8;
        ((f16x8*)(Alo + t * 256))[ss] = l8;
    }

    // ---- 8 residual-VQ layers, residual resident in LDS ----
#pragma unroll 1
    for (int q = 0; q < NQ; ++q) {
        const _Float16* embedBq = embedB + q * 524288;
        const float*    embedTq = embedT + q * (KCODES * DIMV);

        // stage this layer's e2 into LDS (broadcast-read in score phase)
        e2Lds[tid]       = e2[q * KCODES + tid];
        e2Lds[tid + 512] = e2[q * KCODES + tid + 512];
        // BARRIER 1: fences A/e2 writes; also orders prev layer's bestS
        // reads (fused phase) before this layer's bestS writes, and prev
        // layer's lossRed writes before the deferred read below.
        __syncthreads();

        // deferred loss flush for layer q-1: one atomic per block per layer
        if (q > 0 && tid == 0) {
            float t = 0.f;
#pragma unroll
            for (int w = 0; w < 8; ++w) t += lossRed[w];
            atomicAdd(lossSum + (q - 1), t);
        }

        // running per-token best over this wave's 128 codes
        float bsv0 = 3.4e38f, bsv1 = 3.4e38f;
        int   biv0 = 0x7fffffff, biv1 = 0x7fffffff;

        // ---- two pass-pairs; each runs TWO concurrent 32-code streams ----
#pragma unroll
        for (int pp = 0; pp < 2; ++pp) {
            f32x16 acc[2][2];   // [ct stream][tt token-tile]
#pragma unroll
            for (int ct = 0; ct < 2; ++ct)
#pragma unroll
                for (int tt = 0; tt < 2; ++tt)
#pragma unroll
                    for (int r = 0; r < 16; ++r) acc[ct][tt][r] = 0.f;

            // image (2*wave + pp) covers codes [wave*128 + pp*64, +64);
            // ct stream 0/1 = the two 32-code halves (offsets 0 / 512 B).
            const char* gI = (const char*)embedBq + (2 * wave + pp) * 4096
                             + h32 * 1024 + l32 * 16;

#pragma unroll
            for (int c = 0; c < 16; ++c) {
                const char* gC = gI + c * 65536;
                // B: single-buffered, 4 dwordx4 from one 4 KB image
                const f16x8 bH0 = *(const f16x8*)(gC);
                const f16x8 bH1 = *(const f16x8*)(gC + 512);
                const f16x8 bL0 = *(const f16x8*)(gC + 2048);
                const f16x8 bL1 = *(const f16x8*)(gC + 2560);
                // A: shared by both ct streams (the LDS-read halving)
                f16x8 aH[2], aL[2];
#pragma unroll
                for (int tt = 0; tt < 2; ++tt) {
                    const int t  = tt * 32 + l32;
                    const int ss = rotl3(2 * c + h32) ^ l32;
                    aH[tt] = ((const f16x8*)(Ahi + t * 256))[ss];
                    aL[tt] = ((const f16x8*)(Alo + t * 256))[ss];
                }
                // swapped operands: D[code_row][token_col]; per-code chain
                // order (H*H, L*H, H*L; chunks ascending) identical to the
                // verified kernel -> bit-identical scores.
#pragma unroll
                for (int tt = 0; tt < 2; ++tt) {
                    acc[0][tt] = __builtin_amdgcn_mfma_f32_32x32x16_f16(
                        bH0, aH[tt], acc[0][tt], 0, 0, 0);
                    acc[0][tt] = __builtin_amdgcn_mfma_f32_32x32x16_f16(
                        bL0, aH[tt], acc[0][tt], 0, 0, 0);
                    acc[0][tt] = __builtin_amdgcn_mfma_f32_32x32x16_f16(
                        bH0, aL[tt], acc[0][tt], 0, 0, 0);
                    acc[1][tt] = __builtin_amdgcn_mfma_f32_32x32x16_f16(
                        bH1, aH[tt], acc[1][tt], 0, 0, 0);
                    acc[1][tt] = __builtin_amdgcn_mfma_f32_32x32x16_f16(
                        bL1, aH[tt], acc[1][tt], 0, 0, 0);
                    acc[1][tt] = __builtin_amdgcn_mfma_f32_32x32x16_f16(
                        bH1, aL[tt], acc[1][tt], 0, 0, 0);
                }
            }

            // scores for this pair's 64 codes; fold into running best
#pragma unroll
            for (int ct = 0; ct < 2; ++ct)
#pragma unroll
                for (int tt = 0; tt < 2; ++tt) {
                    float bs = (tt == 0) ? bsv0 : bsv1;
                    int   bi = (tt == 0) ? biv0 : biv1;
#pragma unroll
                    for (int r = 0; r < 16; ++r) {
                        const int cd = wave * 128 + pp * 64 + ct * 32
                                     + (r & 3) + 8 * (r >> 2) + 4 * h32;
                        const float sc = e2Lds[cd] - 2.0f * acc[ct][tt][r];
                        if (sc < bs || (sc == bs && cd < bi)) { bs = sc; bi = cd; }
                    }
                    if (tt == 0) { bsv0 = bs; biv0 = bi; } else { bsv1 = bs; biv1 = bi; }
                }
        }

        // ---- merge with the other 32-lane half, write per-wave best ----
#pragma unroll
        for (int tt = 0; tt < 2; ++tt) {
            float bs = (tt == 0) ? bsv0 : bsv1;
            int   bi = (tt == 0) ? biv0 : biv1;
            const float so = __shfl_xor(bs, 32);
            const int   io = __shfl_xor(bi, 32);
            if (so < bs || (so == bs && io < bi)) { bs = so; bi = io; }
            if (h32 == 0) {
                bestS[wave * 65 + tt * 32 + l32] = bs;
                bestI[wave * 65 + tt * 32 + l32] = bi;
            }
        }
        // BARRIER 2: bestS/bestI visible; separates K-loop A-reads from
        // the update phase's A-writes.
        __syncthreads();

        // ---- fused argmin + gather + update (no extra barrier):
        // thread (tl=tid>>3, g=tid&7) merges the 8 wave-entries for its
        // token via shuffle; afterwards EVERY thread holds the winning
        // code, which is exactly the update phase's (tl,sg) mapping.
        {
            const int tl = tid >> 3;          // token 0..63
            const int g  = tid & 7;           // wave index / 32-dim strip
            float bs = bestS[g * 65 + tl];
            int   bi = bestI[g * 65 + tl];
#pragma unroll
            for (int m = 1; m < 8; m <<= 1) {
                const float so = __shfl_xor(bs, m);
                const int   io = __shfl_xor(bi, m);
                if (so < bs || (so == bs && io < bi)) { bs = so; bi = io; }
            }
            if (g == 0) atomicAdd(&counts[q * KCODES + bi], 1);

            // update: r -= quantize (in LDS); loss partial
            const float* gq = embedTq + bi * 256;
            float lp = 0.f;
            f16x8* rowH = (f16x8*)(Ahi + tl * 256);
            f16x8* rowL = (f16x8*)(Alo + tl * 256);
#pragma unroll
            for (int it = 0; it < 4; ++it) {
                const int slotIdx = g * 4 + it;           // 0..31
                const int slot = rotl3(slotIdx) ^ (tl & 31);
                f16x8 h8 = rowH[slot];
                f16x8 l8 = rowL[slot];
                const float4 q0 = *(const float4*)(gq + slotIdx * 8);
                const float4 q1 = *(const float4*)(gq + slotIdx * 8 + 4);
                const float qv[8] = {q0.x, q0.y, q0.z, q0.w, q1.x, q1.y, q1.z, q1.w};
#pragma unroll
                for (int e = 0; e < 8; ++e) {
                    const float rv = (float)h8[e] + (float)l8[e];
                    const float nr = rv - qv[e];
                    lp += nr * nr;
                    const _Float16 nh = (_Float16)nr;
                    h8[e] = nh;
                    l8[e] = (_Float16)(nr - (float)nh);
                }
                rowH[slot] = h8;
                rowL[slot] = l8;
            }
            // loss: wave shuffle-reduce -> lossRed[wave] (flushed next layer)
#pragma unroll
            for (int off = 32; off > 0; off >>= 1) lp += __shfl_down(lp, off);
            if (lane == 0) lossRed[wave] = lp;
        }
        // no trailing barrier: next layer's B1 fences A/bestS/lossRed.
    }

    __syncthreads();   // final update + lossRed writes -> reads below

    // deferred loss flush for the last layer
    if (tid == 0) {
        float t = 0.f;
#pragma unroll
        for (int w = 0; w < 8; ++w) t += lossRed[w];
        atomicAdd(lossSum + (NQ - 1), t);
    }

    // ---- writeback: out = x - residual_final, coalesced ----
#pragma unroll
    for (int k = 0; k < 4; ++k) {
        const int si = tid + k * 512;
        const int t  = si >> 5;
        const int s  = si & 31;
        const int ss = rotl3(s) ^ (t & 31);
        const f16x8 h8 = ((const f16x8*)(Ahi + t * 256))[ss];
        const f16x8 l8 = ((const f16x8*)(Alo + t * 256))[ss];
        const float4 x0 = *(const float4*)(x + (tok0 + t) * 256 + s * 8);
        const float4 x1 = *(const float4*)(x + (tok0 + t) * 256 + s * 8 + 4);
        float4 o0, o1;
        o0.x = x0.x - ((float)h8[0] + (float)l8[0]);
        o0.y = x0.y - ((float)h8[1] + (float)l8[1]);
        o0.z = x0.z - ((float)h8[2] + (float)l8[2]);
        o0.w = x0.w - ((float)h8[3] + (float)l8[3]);
        o1.x = x1.x - ((float)h8[4] + (float)l8[4]);
        o1.y = x1.y - ((float)h8[5] + (float)l8[5]);
        o1.z = x1.z - ((float)h8[6] + (float)l8[6]);
        o1.w = x1.w - ((float)h8[7] + (float)l8[7]);
        *(float4*)(out + (tok0 + t) * 256 + s * 8)     = o0;
        *(float4*)(out + (tok0 + t) * 256 + s * 8 + 4) = o1;
    }
}

// ---------------------------------------------------------------------------
// Finalize: losses + perplexities into the output tail.
// ---------------------------------------------------------------------------
__global__ __launch_bounds__(256)
void vq_finalize(const int* __restrict__ counts, const float* __restrict__ lossSum,
                 float* __restrict__ outTail) {
    const int q = blockIdx.x;
    const int tid = threadIdx.x;
    float s = 0.f;
    for (int k = tid; k < KCODES; k += 256) {
        const float p = (float)counts[q * KCODES + k] * (1.0f / 65536.0f);
        s += p * logf(p + 1e-10f);
    }
    for (int off = 32; off > 0; off >>= 1) s += __shfl_down(s, off);
    __shared__ float wpart[4];
    if ((tid & 63) == 0) wpart[tid >> 6] = s;
    __syncthreads();
    if (tid == 0) {
        outTail[q]     = lossSum[q] * (1.0f / 16777216.0f);   // mean * COMMITMENT
        outTail[8 + q] = expf(-(wpart[0] + wpart[1] + wpart[2] + wpart[3]));
    }
}

// ---------------------------------------------------------------------------
extern "C" void kernel_launch(void* const* d_in, const int* in_sizes, int n_in,
                              void* d_out, int out_size, void* d_ws, size_t ws_size,
                              hipStream_t stream) {
    const float* x      = (const float*)d_in[0];   // [32,2048,256]
    const float* embeds = (const float*)d_in[1];   // [8,256,1024]
    float* out = (float*)d_out;                    // 16777216 + 8 + 8

    // Workspace layout (float units unless noted):
    float* embedT   = (float*)d_ws;                     // 2,097,152
    float* e2       = embedT + 2097152;                 // 8,192
    float* lossSum  = e2 + 8192;                        // 8
    int*   counts   = (int*)(lossSum + 8);              // 8,192
    _Float16* embedB = (_Float16*)(counts + 8192);      // 4,194,304 halfs (8 MB)

    hipMemsetAsync(lossSum, 0, (8 + 8192) * sizeof(float), stream);

    vq_transpose<<<8192, 256, 0, stream>>>(embeds, embedT);
    vq_e2<<<32, 256, 0, stream>>>(embeds, e2);
    vq_embedB<<<16384, 256, 0, stream>>>(embeds, embedB);

    hipFuncSetAttribute((const void*)vq_fused,
                        hipFuncAttributeMaxDynamicSharedMemorySize, LDS_BYTES);
    vq_fused<<<NTOK / TOKPB, 512, LDS_BYTES, stream>>>(
        x, out, embedT, e2, embedB, lossSum, counts);

    vq_finalize<<<NQ, 256, 0, stream>>>(counts, lossSum, out + NELEM);
}